// Round 1
// baseline (2359.414 us; speedup 1.0000x reference)
//
#include <hip/hip_runtime.h>
#include <math.h>

// ---------------- problem constants ----------------
constexpr int BSZ = 16;
constexpr int PCAPS = 15488;           // 32 maps * 22*22
// workspace layout (float offsets)
constexpr size_t OFF_X    = 0;                       // conv1 out [16][256][52][52]
constexpr size_t N_X      = (size_t)16*256*52*52;    // 11075584
constexpr size_t OFF_WT   = OFF_X + N_X;             // wT [20736][256]
constexpr size_t N_WT     = (size_t)20736*256;       // 5308416
constexpr size_t OFF_U    = OFF_WT + N_WT;           // u [16][15488][8]
constexpr size_t N_U      = (size_t)16*15488*8;      // 1982464
constexpr size_t OFF_PC   = OFF_U + N_U;             // pc partials [2][16][256][484]
constexpr size_t N_PCH    = (size_t)16*256*484;      // 1982464
constexpr size_t OFF_UACC = OFF_PC + 2*N_PCH;        // U [16][8]
constexpr size_t OFF_Z1   = OFF_UACC + 128;          // [16][10]
constexpr size_t OFF_TU1  = OFF_Z1 + 160;            // [16][10][8]
constexpr size_t OFF_Z2   = OFF_TU1 + 1280;
constexpr size_t OFF_TU2  = OFF_Z2 + 160;
constexpr size_t OFF_WVS  = OFF_TU2 + 1280;          // WvSum [16][10][8]
constexpr size_t OFF_V    = OFF_WVS + 1280;          // v [16][10][16]
constexpr size_t OFF_M    = OFF_V + 2560;            // masked caps [16][160]
constexpr size_t OFF_H1   = OFF_M + 2560;            // [16][512]
constexpr size_t OFF_H2   = OFF_H1 + 8192;           // [16][1024]
// zero region = UACC..TU2 end = 128+160+1280+160+1280 = 3008 floats

// ---------------- weight transpose: w[oc][k] -> wT[k][oc], k = ic*81+kh*9+kw
__global__ __launch_bounds__(256) void wtrans_kernel(const float* __restrict__ w,
                                                     float* __restrict__ wT)
{
    __shared__ float tile[64][65];
    const int k0 = blockIdx.x * 64;      // 324 blocks
    const int o0 = blockIdx.y * 64;      // 4 blocks
    const int tx = threadIdx.x & 63;
    const int ty = threadIdx.x >> 6;
    for (int r = ty; r < 64; r += 4)
        tile[r][tx] = w[(size_t)(o0 + r)*20736 + k0 + tx];
    __syncthreads();
    for (int r = ty; r < 64; r += 4)
        wT[(size_t)(k0 + r)*256 + o0 + tx] = tile[tx][r];
}

// ---------------- conv1 + relu: imgs[16][1][60][60] -> x[16][256][52][52]
__global__ __launch_bounds__(256) void conv1_kernel(const float* __restrict__ imgs,
                                                    const float* __restrict__ w,
                                                    const float* __restrict__ bias,
                                                    float* __restrict__ x)
{
    __shared__ float simg[3600];
    __shared__ float sw[81];
    const int oc = blockIdx.x, b = blockIdx.y, t = threadIdx.x;
    const float* ib = imgs + (size_t)b * 3600;
    for (int i = t; i < 3600; i += 256) simg[i] = ib[i];
    if (t < 81) sw[t] = w[(size_t)oc*81 + t];
    __syncthreads();
    const float bv = bias[oc];
    // 52 rows x 13 groups of 4 output cols
    for (int g = t; g < 676; g += 256) {
        const int oh = g / 13;
        const int owg = (g - oh*13) * 4;
        float a0 = 0.f, a1 = 0.f, a2 = 0.f, a3 = 0.f;
        for (int kh = 0; kh < 9; ++kh) {
            const float4* r4 = (const float4*)(&simg[(oh + kh)*60 + owg]);
            const float4 ra = r4[0], rb = r4[1], rc = r4[2];
            const float r[12] = {ra.x,ra.y,ra.z,ra.w, rb.x,rb.y,rb.z,rb.w, rc.x,rc.y,rc.z,rc.w};
            const float* wr = &sw[kh*9];
            #pragma unroll
            for (int kw = 0; kw < 9; ++kw) {
                const float wv = wr[kw];
                a0 = fmaf(wv, r[kw+0], a0);
                a1 = fmaf(wv, r[kw+1], a1);
                a2 = fmaf(wv, r[kw+2], a2);
                a3 = fmaf(wv, r[kw+3], a3);
            }
        }
        float* o = x + ((size_t)(b*256 + oc))*2704 + oh*52 + owg;
        o[0] = fmaxf(a0 + bv, 0.f);
        o[1] = fmaxf(a1 + bv, 0.f);
        o[2] = fmaxf(a2 + bv, 0.f);
        o[3] = fmaxf(a3 + bv, 0.f);
    }
}

// ---------------- primary caps conv (stride 2): x -> pc partial (ic half)
__global__ __launch_bounds__(128) void pconv_kernel(const float* __restrict__ x,
                                                    const float* __restrict__ wT,
                                                    float* __restrict__ pc)
{
    const int t   = threadIdx.x;
    const int ocg = blockIdx.x & 1;
    const int ich = blockIdx.x >> 1;
    const int oh  = blockIdx.y;
    const int b   = blockIdx.z;
    const int oc  = ocg * 128 + t;
    float acc[22];
    #pragma unroll
    for (int i = 0; i < 22; ++i) acc[i] = 0.f;
    const int r0 = oh * 2;
    for (int icl = 0; icl < 128; ++icl) {
        const int ic = ich * 128 + icl;
        const float* xrow = x + ((size_t)(b*256 + ic)*52 + r0)*52;
        for (int kh = 0; kh < 9; ++kh) {
            float xr[52];
            const float4* x4 = (const float4*)(xrow + kh*52);
            #pragma unroll
            for (int q = 0; q < 13; ++q) {
                const float4 vv = x4[q];
                xr[4*q+0] = vv.x; xr[4*q+1] = vv.y; xr[4*q+2] = vv.z; xr[4*q+3] = vv.w;
            }
            const float* wp = wT + (size_t)((ic*9 + kh)*9)*256 + oc;
            #pragma unroll
            for (int kw = 0; kw < 9; ++kw) {
                const float wv = wp[(size_t)kw * 256];
                #pragma unroll
                for (int ow = 0; ow < 22; ++ow)
                    acc[ow] = fmaf(wv, xr[2*ow + kw], acc[ow]);
            }
        }
    }
    float2* out = (float2*)(pc + (size_t)ich*N_PCH + (size_t)(b*256 + oc)*484 + oh*22);
    #pragma unroll
    for (int i = 0; i < 11; ++i) out[i] = make_float2(acc[2*i], acc[2*i+1]);
}

// ---------------- primary squash: pc(2 partials)+bias -> u[b][p][8]; U[b][e]=sum_p u
__global__ __launch_bounds__(256) void psquash_kernel(const float* __restrict__ pc,
                                                      const float* __restrict__ bias,
                                                      float* __restrict__ u,
                                                      float* __restrict__ Uacc)
{
    const int b = blockIdx.y;
    const int p = blockIdx.x*256 + threadIdx.x;
    float u8[8];
    #pragma unroll
    for (int e = 0; e < 8; ++e) u8[e] = 0.f;
    if (p < PCAPS) {
        const int m = p / 484;
        const int s = p - m*484;
        float sq = 0.f;
        #pragma unroll
        for (int e = 0; e < 8; ++e) {
            const int ch = e*32 + m;                 // channel = e*32 + m
            const size_t idx = ((size_t)(b*256 + ch))*484 + s;
            const float val = pc[idx] + pc[N_PCH + idx] + bias[ch];
            u8[e] = val; sq += val*val;
        }
        const float scale = (sq / (1.f + sq)) / sqrtf(sq + 1e-8f);
        #pragma unroll
        for (int e = 0; e < 8; ++e) u8[e] *= scale;
        float4* up = (float4*)(u + ((size_t)b*PCAPS + p)*8);
        up[0] = make_float4(u8[0], u8[1], u8[2], u8[3]);
        up[1] = make_float4(u8[4], u8[5], u8[6], u8[7]);
    }
    #pragma unroll
    for (int off = 32; off > 0; off >>= 1) {
        #pragma unroll
        for (int e = 0; e < 8; ++e) u8[e] += __shfl_down(u8[e], off, 64);
    }
    if ((threadIdx.x & 63) == 0) {
        #pragma unroll
        for (int e = 0; e < 8; ++e) atomicAdd(&Uacc[b*8 + e], u8[e]);
    }
}

// ---------------- routing big pass: Z[b][c]=sum_p exp(u.Wv), tu[b][c][e]=sum_p exp*u
__global__ __launch_bounds__(256) void route_pass(const float* __restrict__ u,
                                                  const float* __restrict__ Wv,
                                                  float* __restrict__ Z,
                                                  float* __restrict__ tu)
{
    const int b = blockIdx.y;
    const int t = threadIdx.x;
    __shared__ float sWv[80];
    if (t < 80) sWv[t] = Wv[b*80 + t];
    __syncthreads();
    float accZ[10];
    float accT[80];
    #pragma unroll
    for (int i = 0; i < 10; ++i) accZ[i] = 0.f;
    #pragma unroll
    for (int i = 0; i < 80; ++i) accT[i] = 0.f;
    for (int p = blockIdx.x*256 + t; p < PCAPS; p += 8*256) {
        const float4* up = (const float4*)(u + ((size_t)b*PCAPS + p)*8);
        const float4 ua = up[0], ub = up[1];
        const float u8[8] = {ua.x, ua.y, ua.z, ua.w, ub.x, ub.y, ub.z, ub.w};
        #pragma unroll
        for (int c = 0; c < 10; ++c) {
            float bij = 0.f;
            #pragma unroll
            for (int e = 0; e < 8; ++e) bij = fmaf(u8[e], sWv[c*8 + e], bij);
            const float ex = __expf(bij);
            accZ[c] += ex;
            #pragma unroll
            for (int e = 0; e < 8; ++e) accT[c*8 + e] = fmaf(ex, u8[e], accT[c*8 + e]);
        }
    }
    #pragma unroll
    for (int off = 32; off > 0; off >>= 1) {
        #pragma unroll
        for (int i = 0; i < 10; ++i) accZ[i] += __shfl_down(accZ[i], off, 64);
        #pragma unroll
        for (int i = 0; i < 80; ++i) accT[i] += __shfl_down(accT[i], off, 64);
    }
    if ((t & 63) == 0) {
        #pragma unroll
        for (int c = 0; c < 10; ++c) atomicAdd(&Z[b*10 + c], accZ[c]);
        #pragma unroll
        for (int i = 0; i < 80; ++i) atomicAdd(&tu[b*80 + i], accT[i]);
    }
}

// ---------------- tiny per-(b,c) routing step: s_j = W.tu/Z, v = squash, WvSum += W^T.v
__global__ void route_small_kernel(const float* __restrict__ W,
                                   const float* __restrict__ tu,
                                   const float* __restrict__ Z,
                                   const float* __restrict__ Uacc,
                                   float* __restrict__ v,
                                   float* __restrict__ WvSum,
                                   int mode)   // 0: first iter (uniform c_ij), 1: accumulate, 2: final
{
    const int t = threadIdx.x;
    if (t >= 160) return;
    const int b = t / 10, c = t - b*10;
    float te[8];
    float zinv;
    if (mode == 0) {
        #pragma unroll
        for (int e = 0; e < 8; ++e) te[e] = Uacc[b*8 + e];
        zinv = 1.f / (float)PCAPS;
    } else {
        #pragma unroll
        for (int e = 0; e < 8; ++e) te[e] = tu[(b*10 + c)*8 + e];
        zinv = 1.f / Z[b*10 + c];
    }
    float s[16];
    float sq = 0.f;
    #pragma unroll
    for (int d = 0; d < 16; ++d) {
        float a = 0.f;
        #pragma unroll
        for (int e = 0; e < 8; ++e) a = fmaf(W[(c*16 + d)*8 + e], te[e], a);
        a *= zinv;
        s[d] = a; sq += a*a;
    }
    const float scale = (sq / (1.f + sq)) / sqrtf(sq + 1e-8f);
    #pragma unroll
    for (int d = 0; d < 16; ++d) { s[d] *= scale; v[(b*10 + c)*16 + d] = s[d]; }
    if (mode != 2) {
        #pragma unroll
        for (int e = 0; e < 8; ++e) {
            float a = 0.f;
            #pragma unroll
            for (int d = 0; d < 16; ++d) a = fmaf(W[(c*16 + d)*8 + e], s[d], a);
            WvSum[(b*10 + c)*8 + e] = (mode == 0) ? a : (WvSum[(b*10 + c)*8 + e] + a);
        }
    }
}

// ---------------- head: v_length, argmax, one-hot, masked caps
__global__ __launch_bounds__(256) void head_kernel(const float* __restrict__ v,
                                                   float* __restrict__ y_out,
                                                   float* __restrict__ vlen_out,
                                                   float* __restrict__ m)
{
    __shared__ float lv[160];
    __shared__ int amax[16];
    const int t = threadIdx.x;
    if (t < 160) {
        const int b = t / 10, c = t - b*10;
        float s = 0.f;
        #pragma unroll
        for (int d = 0; d < 16; ++d) { const float xv = v[(b*10 + c)*16 + d]; s += xv*xv; }
        const float L = sqrtf(s);
        lv[t] = L;
        vlen_out[t] = L;
    }
    __syncthreads();
    if (t < 16) {
        int best = 0; float bv = lv[t*10];
        for (int c = 1; c < 10; ++c) { const float val = lv[t*10 + c]; if (val > bv) { bv = val; best = c; } }
        amax[t] = best;
    }
    __syncthreads();
    if (t < 160) y_out[t] = ((t % 10) == amax[t / 10]) ? 1.0f : 0.0f;
    for (int i = t; i < 2560; i += 256) {
        const int b = i / 160, cd = i - b*160, c = cd / 16;
        m[i] = (c == amax[b]) ? v[b*160 + cd] : 0.0f;
    }
}

// ---------------- dense layer: out[b][j] = act(in[b][:] . W[:,j] + bias[j])
__global__ __launch_bounds__(256) void fc_kernel(const float* __restrict__ in,
                                                 const float* __restrict__ Wm,
                                                 const float* __restrict__ bias,
                                                 float* __restrict__ out,
                                                 int K, int N, int act)
{
    const int j = blockIdx.x*256 + threadIdx.x;
    const int b = blockIdx.y;
    if (j >= N) return;
    float a = bias[j];
    const float* ib = in + (size_t)b * K;
    for (int k = 0; k < K; ++k) a = fmaf(ib[k], Wm[(size_t)k*N + j], a);
    out[(size_t)b*N + j] = (act == 0) ? fmaxf(a, 0.f) : 1.f / (1.f + __expf(-a));
}

extern "C" void kernel_launch(void* const* d_in, const int* in_sizes, int n_in,
                              void* d_out, int out_size, void* d_ws, size_t ws_size,
                              hipStream_t stream)
{
    const float* imgs = (const float*)d_in[0];
    const float* c1w  = (const float*)d_in[1];
    const float* c1b  = (const float*)d_in[2];
    const float* pw   = (const float*)d_in[3];
    const float* pb   = (const float*)d_in[4];
    const float* Wd   = (const float*)d_in[5];
    const float* w1   = (const float*)d_in[6];
    const float* b1   = (const float*)d_in[7];
    const float* w2   = (const float*)d_in[8];
    const float* b2   = (const float*)d_in[9];
    const float* w3   = (const float*)d_in[10];
    const float* b3   = (const float*)d_in[11];

    float* ws  = (float*)d_ws;
    float* out = (float*)d_out;

    float* x    = ws + OFF_X;
    float* wT   = ws + OFF_WT;
    float* u    = ws + OFF_U;
    float* pc   = ws + OFF_PC;
    float* Uacc = ws + OFF_UACC;
    float* Z1   = ws + OFF_Z1;
    float* tu1  = ws + OFF_TU1;
    float* Z2   = ws + OFF_Z2;
    float* tu2  = ws + OFF_TU2;
    float* Wvs  = ws + OFF_WVS;
    float* v    = ws + OFF_V;
    float* m    = ws + OFF_M;
    float* h1   = ws + OFF_H1;
    float* h2   = ws + OFF_H2;

    // zero the reduction accumulators (U, Z1, tu1, Z2, tu2 contiguous)
    hipMemsetAsync(ws + OFF_UACC, 0, 3008 * sizeof(float), stream);

    wtrans_kernel<<<dim3(324, 4), 256, 0, stream>>>(pw, wT);
    conv1_kernel<<<dim3(256, 16), 256, 0, stream>>>(imgs, c1w, c1b, x);
    pconv_kernel<<<dim3(4, 22, 16), 128, 0, stream>>>(x, wT, pc);
    psquash_kernel<<<dim3(61, 16), 256, 0, stream>>>(pc, pb, u, Uacc);

    // routing iter 0 (uniform c_ij): v0, WvSum = Wv(v0)
    route_small_kernel<<<1, 192, 0, stream>>>(Wd, tu1, Z1, Uacc, v, Wvs, 0);
    // routing iter 1
    route_pass<<<dim3(8, 16), 256, 0, stream>>>(u, Wvs, Z1, tu1);
    route_small_kernel<<<1, 192, 0, stream>>>(Wd, tu1, Z1, Uacc, v, Wvs, 1);
    // routing iter 2 (final)
    route_pass<<<dim3(8, 16), 256, 0, stream>>>(u, Wvs, Z2, tu2);
    route_small_kernel<<<1, 192, 0, stream>>>(Wd, tu2, Z2, Uacc, v, Wvs, 2);

    // head + decoder. out layout: [y_ohe 160][reconst 57600][v_length 160]
    head_kernel<<<1, 256, 0, stream>>>(v, out, out + 160 + 57600, m);
    fc_kernel<<<dim3(2, 16), 256, 0, stream>>>(m,  w1, b1, h1, 160, 512, 0);
    fc_kernel<<<dim3(4, 16), 256, 0, stream>>>(h1, w2, b2, h2, 512, 1024, 0);
    fc_kernel<<<dim3(15, 16), 256, 0, stream>>>(h2, w3, b3, out + 160, 1024, 3600, 1);
}

// Round 2
// 970.794 us; speedup vs baseline: 2.4304x; 2.4304x over previous
//
#include <hip/hip_runtime.h>
#include <hip/hip_bf16.h>
#include <math.h>

typedef __attribute__((ext_vector_type(8))) short bf16x8;
typedef __attribute__((ext_vector_type(4))) float f32x4;

constexpr int PCAPS = 15488;                       // 32 maps * 484
constexpr size_t NPCH = (size_t)16*256*484;        // floats per pc partial

// ---- workspace layout (bytes) ----
constexpr size_t OFF_XC_B = 0;                                   // xc bf16 [16][52][2][28][256]
constexpr size_t XC_BYTES = (size_t)16*52*2*28*256*2;            // 23,855,104
constexpr size_t OFF_WA_B = OFF_XC_B + XC_BYTES;                 // wA bf16 [256][81][256]
constexpr size_t WA_BYTES = (size_t)256*20736*2;                 // 10,616,832
constexpr size_t OFF_PC_B = OFF_WA_B + WA_BYTES;                 // pc f32 [4][16][256][484]
constexpr size_t PC_BYTES = (size_t)4*NPCH*4;
constexpr size_t OFF_U_B  = OFF_PC_B + PC_BYTES;                 // u f32 [16][15488][8]
constexpr size_t U_BYTES  = (size_t)16*PCAPS*8*4;
constexpr size_t OFF_SM_B = OFF_U_B + U_BYTES;                   // small region (floats)
// small region offsets (in floats, relative to small base)
constexpr int S_UACC = 0;      // 128
constexpr int S_Z1   = 128;    // 160
constexpr int S_TU1  = 288;    // 1280
constexpr int S_Z2   = 1568;   // 160
constexpr int S_TU2  = 1728;   // 1280  -> zero region = 3008 floats
constexpr int S_WVS  = 3008;   // 1280
constexpr int S_V    = 4288;   // 2560
constexpr int S_M    = 6848;   // 2560
constexpr int S_H1   = 9408;   // 8192
constexpr int S_H2   = 17600;  // 16384

// ---------------- weight prepack: pw[oc][ic*81+khw] f32 -> wA[oc][khw][ic] bf16
__global__ __launch_bounds__(256) void wprep_kernel(const float* __restrict__ pw,
                                                    __hip_bfloat16* __restrict__ wA)
{
    const int oc = blockIdx.x, t = threadIdx.x;   // t = ic
    const float* src = pw + (size_t)oc*20736;
    __hip_bfloat16* dst = wA + (size_t)oc*20736;
    for (int khw = 0; khw < 81; ++khw)
        dst[khw*256 + t] = __float2bfloat16(src[t*81 + khw]);
}

// ---------------- conv1 + relu, channel-last bf16 parity-split output
// xc[b][h][p][wc][ic], p = w&1, wc = w>>1  (wc dim 28, cols 26..27 stay zero)
__global__ __launch_bounds__(256) void conv1_cl(const float* __restrict__ imgs,
                                                const float* __restrict__ w,
                                                const float* __restrict__ bias,
                                                __hip_bfloat16* __restrict__ xc)
{
    __shared__ float simg[540];
    const int h = blockIdx.x, b = blockIdx.y, t = threadIdx.x;   // t = oc
    const float* ib = imgs + (size_t)b*3600 + h*60;
    for (int i = t; i < 540; i += 256) simg[i] = ib[i];
    float wr[81];
    const float* wp = w + (size_t)t*81;
    #pragma unroll
    for (int j = 0; j < 81; ++j) wr[j] = wp[j];
    __syncthreads();
    const float bv = bias[t];
    __hip_bfloat16* xb = xc + ((size_t)b*52 + h)*2*28*256 + t;
    for (int g = 0; g < 13; ++g) {
        const int w0 = g*4;
        float a0=0.f, a1=0.f, a2=0.f, a3=0.f;
        #pragma unroll
        for (int kh = 0; kh < 9; ++kh) {
            const float* rp = &simg[kh*60 + w0];
            const float4 A  = *(const float4*)rp;
            const float4 Bv = *(const float4*)(rp+4);
            const float4 C  = *(const float4*)(rp+8);
            const float r[12] = {A.x,A.y,A.z,A.w,Bv.x,Bv.y,Bv.z,Bv.w,C.x,C.y,C.z,C.w};
            const float* ww = &wr[kh*9];
            #pragma unroll
            for (int kw = 0; kw < 9; ++kw) {
                a0 = fmaf(ww[kw], r[kw+0], a0);
                a1 = fmaf(ww[kw], r[kw+1], a1);
                a2 = fmaf(ww[kw], r[kw+2], a2);
                a3 = fmaf(ww[kw], r[kw+3], a3);
            }
        }
        const float vals[4] = {a0,a1,a2,a3};
        #pragma unroll
        for (int q = 0; q < 4; ++q) {
            const int wcol = w0 + q;
            xb[((size_t)(wcol&1)*28 + (wcol>>1))*256] =
                __float2bfloat16(fmaxf(vals[q] + bv, 0.f));
        }
    }
}

// ---------------- primary caps conv as bf16 MFMA implicit GEMM, split-K=4
// grid: x = b*11 + ohp (176), y = kpart (4). 256 threads = 4 waves.
// C-tile 256(m=oc) x 48(n = r*24 + ow padded), per wave 64m x 48n.
__global__ __launch_bounds__(256) void pconv_mfma(const __hip_bfloat16* __restrict__ xc,
                                                  const __hip_bfloat16* __restrict__ wA,
                                                  float* __restrict__ pc)
{
    __shared__ bf16x8 As[2048];   // [256 m][8 k-chunks], chunk index XOR-swizzled
    __shared__ bf16x8 Bs[384];    // [48 n][8 k-chunks]
    const int t = threadIdx.x;
    const int b = blockIdx.x / 11, ohp = blockIdx.x % 11;
    const int kpart = blockIdx.y;
    const int khw0  = (kpart == 0) ? 0 : (1 + 20*kpart);   // 0,21,41,61
    const int niter = (kpart == 0) ? 84 : 80;              // (khw count)*4 ic-chunks

    // A staging: thread t loads rows m=(t>>3)+32*i, 16B chunk j=t&7
    const int arow  = t >> 3;
    const int aj    = t & 7;
    const int aslot = aj ^ (arow & 7);
    const short* wA_s  = (const short*)wA;
    const short* asrc0 = wA_s + (size_t)arow*20736 + khw0*256 + aj*8;

    // B staging: thread t<192 -> n=t>>2, 32B at ic offset (t&3)*16
    const int bn  = t >> 2;
    const int bc4 = t & 3;
    const int brr = (bn >= 24) ? 1 : 0;
    const int bow = bn - 24*brr;
    const short* xc_s = (const short*)xc;
    const size_t xbase = ((size_t)b*52)*2*28*256;

    bf16x8 areg[8], breg[2];
    auto load_regs = [&](int kt) {
        #pragma unroll
        for (int i = 0; i < 8; ++i)
            areg[i] = *(const bf16x8*)(asrc0 + (size_t)i*32*20736 + kt*64);
        if (t < 192) {
            const int khw = khw0 + (kt >> 2), ich = kt & 3;
            const int kh = khw / 9, kw = khw - 9*kh;
            const int h = 4*ohp + 2*brr + kh;
            const short* src = xc_s + xbase
                + (((size_t)h*2 + (kw & 1))*28 + (kw >> 1) + bow)*256 + ich*64 + bc4*16;
            breg[0] = *(const bf16x8*)(src);
            breg[1] = *(const bf16x8*)(src + 8);
        }
    };

    f32x4 acc[4][3];
    const f32x4 z4 = {0.f, 0.f, 0.f, 0.f};
    #pragma unroll
    for (int mt = 0; mt < 4; ++mt)
        #pragma unroll
        for (int nt = 0; nt < 3; ++nt) acc[mt][nt] = z4;

    const int w = t >> 6, lane = t & 63, lm = lane & 15, lk = lane >> 4;
    const int swz = lm & 7;

    load_regs(0);
    for (int kt = 0; kt < niter; ++kt) {
        __syncthreads();              // previous LDS reads done
        #pragma unroll
        for (int i = 0; i < 8; ++i)
            As[(arow + 32*i)*8 + aslot] = areg[i];
        if (t < 192) {
            const int j0 = bc4*2;
            Bs[bn*8 + (j0 ^ (bn & 7))]       = breg[0];
            Bs[bn*8 + ((j0 + 1) ^ (bn & 7))] = breg[1];
        }
        __syncthreads();              // LDS tile ready
        if (kt + 1 < niter) load_regs(kt + 1);   // issue next-tile global loads early
        #pragma unroll
        for (int ks = 0; ks < 2; ++ks) {
            const int chunk = (lk + 4*ks) ^ swz;
            bf16x8 af[4], bfr[3];
            #pragma unroll
            for (int mt = 0; mt < 4; ++mt)
                af[mt] = As[(w*64 + mt*16 + lm)*8 + chunk];
            #pragma unroll
            for (int nt = 0; nt < 3; ++nt)
                bfr[nt] = Bs[(nt*16 + lm)*8 + chunk];
            #pragma unroll
            for (int mt = 0; mt < 4; ++mt)
                #pragma unroll
                for (int nt = 0; nt < 3; ++nt)
                    acc[mt][nt] = __builtin_amdgcn_mfma_f32_16x16x32_bf16(
                        af[mt], bfr[nt], acc[mt][nt], 0, 0, 0);
        }
    }

    // epilogue: D row = (lane>>4)*4+reg, col = lane&15  (m89-verified C/D layout)
    float* pcp = pc + (size_t)kpart*NPCH;
    #pragma unroll
    for (int nt = 0; nt < 3; ++nt) {
        const int nl = nt*16 + lm;
        const int rr = (nl >= 24) ? 1 : 0;
        const int ow = nl - 24*rr;
        if (ow < 22) {
            const int s = (2*ohp + rr)*22 + ow;
            #pragma unroll
            for (int mt = 0; mt < 4; ++mt) {
                #pragma unroll
                for (int r = 0; r < 4; ++r) {
                    const int m = w*64 + mt*16 + lk*4 + r;
                    pcp[((size_t)(b*256 + m))*484 + s] = acc[mt][nt][r];
                }
            }
        }
    }
}

// ---------------- primary squash: sum 4 pc partials + bias -> u; U[b][e] = sum_p u
__global__ __launch_bounds__(256) void psquash_kernel(const float* __restrict__ pc,
                                                      const float* __restrict__ bias,
                                                      float* __restrict__ u,
                                                      float* __restrict__ Uacc)
{
    const int b = blockIdx.y;
    const int p = blockIdx.x*256 + threadIdx.x;
    float u8[8];
    #pragma unroll
    for (int e = 0; e < 8; ++e) u8[e] = 0.f;
    if (p < PCAPS) {
        const int m = p / 484;
        const int s = p - m*484;
        float sq = 0.f;
        #pragma unroll
        for (int e = 0; e < 8; ++e) {
            const int ch = e*32 + m;
            const size_t idx = ((size_t)(b*256 + ch))*484 + s;
            const float val = pc[idx] + pc[NPCH + idx] + pc[2*NPCH + idx] + pc[3*NPCH + idx]
                            + bias[ch];
            u8[e] = val; sq += val*val;
        }
        const float scale = (sq / (1.f + sq)) / sqrtf(sq + 1e-8f);
        #pragma unroll
        for (int e = 0; e < 8; ++e) u8[e] *= scale;
        float4* up = (float4*)(u + ((size_t)b*PCAPS + p)*8);
        up[0] = make_float4(u8[0], u8[1], u8[2], u8[3]);
        up[1] = make_float4(u8[4], u8[5], u8[6], u8[7]);
    }
    #pragma unroll
    for (int off = 32; off > 0; off >>= 1) {
        #pragma unroll
        for (int e = 0; e < 8; ++e) u8[e] += __shfl_down(u8[e], off, 64);
    }
    if ((threadIdx.x & 63) == 0) {
        #pragma unroll
        for (int e = 0; e < 8; ++e) atomicAdd(&Uacc[b*8 + e], u8[e]);
    }
}

// ---------------- routing big pass: Z[b][c]=sum_p exp(u.Wv), tu[b][c][e]=sum_p exp*u
__global__ __launch_bounds__(256) void route_pass(const float* __restrict__ u,
                                                  const float* __restrict__ Wv,
                                                  float* __restrict__ Z,
                                                  float* __restrict__ tu)
{
    const int b = blockIdx.y;
    const int t = threadIdx.x;
    __shared__ float sWv[80];
    if (t < 80) sWv[t] = Wv[b*80 + t];
    __syncthreads();
    float accZ[10];
    float accT[80];
    #pragma unroll
    for (int i = 0; i < 10; ++i) accZ[i] = 0.f;
    #pragma unroll
    for (int i = 0; i < 80; ++i) accT[i] = 0.f;
    for (int p = blockIdx.x*256 + t; p < PCAPS; p += 8*256) {
        const float4* up = (const float4*)(u + ((size_t)b*PCAPS + p)*8);
        const float4 ua = up[0], ub = up[1];
        const float u8[8] = {ua.x, ua.y, ua.z, ua.w, ub.x, ub.y, ub.z, ub.w};
        #pragma unroll
        for (int c = 0; c < 10; ++c) {
            float bij = 0.f;
            #pragma unroll
            for (int e = 0; e < 8; ++e) bij = fmaf(u8[e], sWv[c*8 + e], bij);
            const float ex = __expf(bij);
            accZ[c] += ex;
            #pragma unroll
            for (int e = 0; e < 8; ++e) accT[c*8 + e] = fmaf(ex, u8[e], accT[c*8 + e]);
        }
    }
    #pragma unroll
    for (int off = 32; off > 0; off >>= 1) {
        #pragma unroll
        for (int i = 0; i < 10; ++i) accZ[i] += __shfl_down(accZ[i], off, 64);
        #pragma unroll
        for (int i = 0; i < 80; ++i) accT[i] += __shfl_down(accT[i], off, 64);
    }
    if ((t & 63) == 0) {
        #pragma unroll
        for (int c = 0; c < 10; ++c) atomicAdd(&Z[b*10 + c], accZ[c]);
        #pragma unroll
        for (int i = 0; i < 80; ++i) atomicAdd(&tu[b*80 + i], accT[i]);
    }
}

// ---------------- tiny per-(b,c) routing step
__global__ void route_small_kernel(const float* __restrict__ W,
                                   const float* __restrict__ tu,
                                   const float* __restrict__ Z,
                                   const float* __restrict__ Uacc,
                                   float* __restrict__ v,
                                   float* __restrict__ WvSum,
                                   int mode)   // 0: uniform c_ij, 1: accumulate, 2: final
{
    const int t = threadIdx.x;
    if (t >= 160) return;
    const int b = t / 10, c = t - b*10;
    float te[8];
    float zinv;
    if (mode == 0) {
        #pragma unroll
        for (int e = 0; e < 8; ++e) te[e] = Uacc[b*8 + e];
        zinv = 1.f / (float)PCAPS;
    } else {
        #pragma unroll
        for (int e = 0; e < 8; ++e) te[e] = tu[(b*10 + c)*8 + e];
        zinv = 1.f / Z[b*10 + c];
    }
    float s[16];
    float sq = 0.f;
    #pragma unroll
    for (int d = 0; d < 16; ++d) {
        float a = 0.f;
        #pragma unroll
        for (int e = 0; e < 8; ++e) a = fmaf(W[(c*16 + d)*8 + e], te[e], a);
        a *= zinv;
        s[d] = a; sq += a*a;
    }
    const float scale = (sq / (1.f + sq)) / sqrtf(sq + 1e-8f);
    #pragma unroll
    for (int d = 0; d < 16; ++d) { s[d] *= scale; v[(b*10 + c)*16 + d] = s[d]; }
    if (mode != 2) {
        #pragma unroll
        for (int e = 0; e < 8; ++e) {
            float a = 0.f;
            #pragma unroll
            for (int d = 0; d < 16; ++d) a = fmaf(W[(c*16 + d)*8 + e], s[d], a);
            WvSum[(b*10 + c)*8 + e] = (mode == 0) ? a : (WvSum[(b*10 + c)*8 + e] + a);
        }
    }
}

// ---------------- head: v_length, argmax, one-hot, masked caps
__global__ __launch_bounds__(256) void head_kernel(const float* __restrict__ v,
                                                   float* __restrict__ y_out,
                                                   float* __restrict__ vlen_out,
                                                   float* __restrict__ m)
{
    __shared__ float lv[160];
    __shared__ int amax[16];
    const int t = threadIdx.x;
    if (t < 160) {
        const int b = t / 10, c = t - b*10;
        float s = 0.f;
        #pragma unroll
        for (int d = 0; d < 16; ++d) { const float xv = v[(b*10 + c)*16 + d]; s += xv*xv; }
        const float L = sqrtf(s);
        lv[t] = L;
        vlen_out[t] = L;
    }
    __syncthreads();
    if (t < 16) {
        int best = 0; float bv = lv[t*10];
        for (int c = 1; c < 10; ++c) { const float val = lv[t*10 + c]; if (val > bv) { bv = val; best = c; } }
        amax[t] = best;
    }
    __syncthreads();
    if (t < 160) y_out[t] = ((t % 10) == amax[t / 10]) ? 1.0f : 0.0f;
    for (int i = t; i < 2560; i += 256) {
        const int b = i / 160, cd = i - b*160, c = cd / 16;
        m[i] = (c == amax[b]) ? v[b*160 + cd] : 0.0f;
    }
}

// ---------------- dense layer
__global__ __launch_bounds__(256) void fc_kernel(const float* __restrict__ in,
                                                 const float* __restrict__ Wm,
                                                 const float* __restrict__ bias,
                                                 float* __restrict__ out,
                                                 int K, int N, int act)
{
    const int j = blockIdx.x*256 + threadIdx.x;
    const int b = blockIdx.y;
    if (j >= N) return;
    float a = bias[j];
    const float* ib = in + (size_t)b * K;
    for (int k = 0; k < K; ++k) a = fmaf(ib[k], Wm[(size_t)k*N + j], a);
    out[(size_t)b*N + j] = (act == 0) ? fmaxf(a, 0.f) : 1.f / (1.f + __expf(-a));
}

extern "C" void kernel_launch(void* const* d_in, const int* in_sizes, int n_in,
                              void* d_out, int out_size, void* d_ws, size_t ws_size,
                              hipStream_t stream)
{
    const float* imgs = (const float*)d_in[0];
    const float* c1w  = (const float*)d_in[1];
    const float* c1b  = (const float*)d_in[2];
    const float* pw   = (const float*)d_in[3];
    const float* pb   = (const float*)d_in[4];
    const float* Wd   = (const float*)d_in[5];
    const float* w1   = (const float*)d_in[6];
    const float* b1   = (const float*)d_in[7];
    const float* w2   = (const float*)d_in[8];
    const float* b2   = (const float*)d_in[9];
    const float* w3   = (const float*)d_in[10];
    const float* b3   = (const float*)d_in[11];

    char* wsb = (char*)d_ws;
    float* out = (float*)d_out;

    __hip_bfloat16* xcb = (__hip_bfloat16*)(wsb + OFF_XC_B);
    __hip_bfloat16* wAb = (__hip_bfloat16*)(wsb + OFF_WA_B);
    float* pc = (float*)(wsb + OFF_PC_B);
    float* u  = (float*)(wsb + OFF_U_B);
    float* sm = (float*)(wsb + OFF_SM_B);

    float* Uacc = sm + S_UACC;
    float* Z1   = sm + S_Z1;
    float* tu1  = sm + S_TU1;
    float* Z2   = sm + S_Z2;
    float* tu2  = sm + S_TU2;
    float* Wvs  = sm + S_WVS;
    float* v    = sm + S_V;
    float* m    = sm + S_M;
    float* h1   = sm + S_H1;
    float* h2   = sm + S_H2;

    // zero: xc pad columns (whole region) + reduction accumulators
    hipMemsetAsync(xcb, 0, XC_BYTES, stream);
    hipMemsetAsync(sm, 0, 3008 * sizeof(float), stream);

    wprep_kernel<<<dim3(256), 256, 0, stream>>>(pw, wAb);
    conv1_cl<<<dim3(52, 16), 256, 0, stream>>>(imgs, c1w, c1b, xcb);
    pconv_mfma<<<dim3(176, 4), 256, 0, stream>>>(xcb, wAb, pc);
    psquash_kernel<<<dim3(61, 16), 256, 0, stream>>>(pc, pb, u, Uacc);

    // routing iter 0 (uniform c_ij)
    route_small_kernel<<<1, 192, 0, stream>>>(Wd, tu1, Z1, Uacc, v, Wvs, 0);
    // routing iter 1
    route_pass<<<dim3(8, 16), 256, 0, stream>>>(u, Wvs, Z1, tu1);
    route_small_kernel<<<1, 192, 0, stream>>>(Wd, tu1, Z1, Uacc, v, Wvs, 1);
    // routing iter 2 (final)
    route_pass<<<dim3(8, 16), 256, 0, stream>>>(u, Wvs, Z2, tu2);
    route_small_kernel<<<1, 192, 0, stream>>>(Wd, tu2, Z2, Uacc, v, Wvs, 2);

    // head + decoder. out layout: [y_ohe 160][reconst 57600][v_length 160]
    head_kernel<<<1, 256, 0, stream>>>(v, out, out + 160 + 57600, m);
    fc_kernel<<<dim3(2, 16), 256, 0, stream>>>(m,  w1, b1, h1, 160, 512, 0);
    fc_kernel<<<dim3(4, 16), 256, 0, stream>>>(h1, w2, b2, h2, 512, 1024, 0);
    fc_kernel<<<dim3(15, 16), 256, 0, stream>>>(h2, w3, b3, out + 160, 1024, 3600, 1);
}

// Round 3
// 526.665 us; speedup vs baseline: 4.4799x; 1.8433x over previous
//
#include <hip/hip_runtime.h>
#include <hip/hip_bf16.h>
#include <math.h>

typedef __attribute__((ext_vector_type(8))) short bf16x8;
typedef __attribute__((ext_vector_type(4))) float f32x4;

constexpr int PCAPS = 15488;                       // 32 maps * 484
constexpr size_t NPCH = (size_t)16*256*484;        // floats per pc partial

// ---- workspace layout (bytes) ----
constexpr size_t OFF_XC_B = 0;                                   // xc bf16 [16][52][2][28][256]
constexpr size_t XC_BYTES = (size_t)16*52*2*28*256*2;            // 23,855,104
constexpr size_t OFF_WA_B = OFF_XC_B + XC_BYTES;                 // wA bf16 [256][81][256]
constexpr size_t WA_BYTES = (size_t)256*20736*2;                 // 10,616,832
constexpr size_t OFF_PC_B = OFF_WA_B + WA_BYTES;                 // pc f32 [4][16][256][484]
constexpr size_t PC_BYTES = (size_t)4*NPCH*4;
constexpr size_t OFF_U_B  = OFF_PC_B + PC_BYTES;                 // u f32 [16][15488][8]
constexpr size_t U_BYTES  = (size_t)16*PCAPS*8*4;
constexpr size_t OFF_SM_B = OFF_U_B + U_BYTES;                   // small region (floats)
// small region offsets (floats, relative to small base)
constexpr int S_UACC = 0;      // 128
constexpr int S_Z1   = 128;    // 160
constexpr int S_TU1  = 288;    // 1280
constexpr int S_Z2   = 1568;   // 160
constexpr int S_TU2  = 1728;   // 1280  -> zero region = 3008 floats
constexpr int S_WVS  = 3008;   // 1280
constexpr int S_V    = 4288;   // 2560
constexpr int S_M    = 6848;   // 2560
constexpr int S_ZD1  = 9408;   // 8192   decoder z1 [16][512]
constexpr int S_ZD2  = 17600;  // 16384  decoder z2 [16][1024]
constexpr int S_ZD3  = 33984;  // 57600  decoder z3 [16][3600]
constexpr int S_W1T  = 91584;  // 20736  conv1 wT [81][256]

// ---------------- weight prepack: pw[oc][ic*81+khw] f32 -> wA[oc][khw][ic] bf16
__global__ __launch_bounds__(256) void wprep_kernel(const float* __restrict__ pw,
                                                    __hip_bfloat16* __restrict__ wA)
{
    const int oc = blockIdx.x, t = threadIdx.x;   // t = ic
    const float* src = pw + (size_t)oc*20736;
    __hip_bfloat16* dst = wA + (size_t)oc*20736;
    for (int khw = 0; khw < 81; ++khw)
        dst[khw*256 + t] = __float2bfloat16(src[t*81 + khw]);
}

// ---------------- conv1 weight transpose: w[oc][j] -> w1T[j][oc] (f32)
__global__ __launch_bounds__(256) void wprep1_kernel(const float* __restrict__ w,
                                                     float* __restrict__ w1T)
{
    const int j = blockIdx.x, t = threadIdx.x;    // t = oc
    w1T[j*256 + t] = w[t*81 + j];
}

// ---------------- conv1 + relu, channel-last bf16 parity-split output
// xc[b][h][p][wc][ic], p = w&1, wc = w>>1  (wc dim 28, cols 26..27 stay zero)
__global__ __launch_bounds__(256) void conv1_cl(const float* __restrict__ imgs,
                                                const float* __restrict__ w1T,
                                                const float* __restrict__ bias,
                                                __hip_bfloat16* __restrict__ xc)
{
    __shared__ float simg[540];
    const int h = blockIdx.x, b = blockIdx.y, t = threadIdx.x;   // t = oc
    const float* ib = imgs + (size_t)b*3600 + h*60;
    for (int i = t; i < 540; i += 256) simg[i] = ib[i];
    float wr[81];
    #pragma unroll
    for (int j = 0; j < 81; ++j) wr[j] = w1T[j*256 + t];   // coalesced, static idx
    __syncthreads();
    const float bv = bias[t];
    __hip_bfloat16* xb = xc + ((size_t)b*52 + h)*2*28*256 + t;
    for (int g = 0; g < 13; ++g) {
        const int w0 = g*4;
        float a0=0.f, a1=0.f, a2=0.f, a3=0.f;
        #pragma unroll
        for (int kh = 0; kh < 9; ++kh) {
            const float* rp = &simg[kh*60 + w0];
            const float4 A  = *(const float4*)rp;
            const float4 Bv = *(const float4*)(rp+4);
            const float4 C  = *(const float4*)(rp+8);
            const float r[12] = {A.x,A.y,A.z,A.w,Bv.x,Bv.y,Bv.z,Bv.w,C.x,C.y,C.z,C.w};
            const float* ww = &wr[kh*9];
            #pragma unroll
            for (int kw = 0; kw < 9; ++kw) {
                a0 = fmaf(ww[kw], r[kw+0], a0);
                a1 = fmaf(ww[kw], r[kw+1], a1);
                a2 = fmaf(ww[kw], r[kw+2], a2);
                a3 = fmaf(ww[kw], r[kw+3], a3);
            }
        }
        const float vals[4] = {a0,a1,a2,a3};
        #pragma unroll
        for (int q = 0; q < 4; ++q) {
            const int wcol = w0 + q;
            xb[((size_t)(wcol&1)*28 + (wcol>>1))*256] =
                __float2bfloat16(fmaxf(vals[q] + bv, 0.f));
        }
    }
}

// ---------------- primary caps conv as bf16 MFMA implicit GEMM, split-K=4
__global__ __launch_bounds__(256) void pconv_mfma(const __hip_bfloat16* __restrict__ xc,
                                                  const __hip_bfloat16* __restrict__ wA,
                                                  float* __restrict__ pc)
{
    __shared__ bf16x8 As[2048];   // [256 m][8 k-chunks], chunk index XOR-swizzled
    __shared__ bf16x8 Bs[384];    // [48 n][8 k-chunks]
    const int t = threadIdx.x;
    const int b = blockIdx.x / 11, ohp = blockIdx.x % 11;
    const int kpart = blockIdx.y;
    const int khw0  = (kpart == 0) ? 0 : (1 + 20*kpart);   // 0,21,41,61
    const int niter = (kpart == 0) ? 84 : 80;              // (khw count)*4 ic-chunks

    const int arow  = t >> 3;
    const int aj    = t & 7;
    const int aslot = aj ^ (arow & 7);
    const short* wA_s  = (const short*)wA;
    const short* asrc0 = wA_s + (size_t)arow*20736 + khw0*256 + aj*8;

    const int bn  = t >> 2;
    const int bc4 = t & 3;
    const int brr = (bn >= 24) ? 1 : 0;
    const int bow = bn - 24*brr;
    const short* xc_s = (const short*)xc;
    const size_t xbase = ((size_t)b*52)*2*28*256;

    bf16x8 areg[8], breg[2];
    auto load_regs = [&](int kt) {
        #pragma unroll
        for (int i = 0; i < 8; ++i)
            areg[i] = *(const bf16x8*)(asrc0 + (size_t)i*32*20736 + kt*64);
        if (t < 192) {
            const int khw = khw0 + (kt >> 2), ich = kt & 3;
            const int kh = khw / 9, kw = khw - 9*kh;
            const int h = 4*ohp + 2*brr + kh;
            const short* src = xc_s + xbase
                + (((size_t)h*2 + (kw & 1))*28 + (kw >> 1) + bow)*256 + ich*64 + bc4*16;
            breg[0] = *(const bf16x8*)(src);
            breg[1] = *(const bf16x8*)(src + 8);
        }
    };

    f32x4 acc[4][3];
    const f32x4 z4 = {0.f, 0.f, 0.f, 0.f};
    #pragma unroll
    for (int mt = 0; mt < 4; ++mt)
        #pragma unroll
        for (int nt = 0; nt < 3; ++nt) acc[mt][nt] = z4;

    const int w = t >> 6, lane = t & 63, lm = lane & 15, lk = lane >> 4;
    const int swz = lm & 7;

    load_regs(0);
    for (int kt = 0; kt < niter; ++kt) {
        __syncthreads();
        #pragma unroll
        for (int i = 0; i < 8; ++i)
            As[(arow + 32*i)*8 + aslot] = areg[i];
        if (t < 192) {
            const int j0 = bc4*2;
            Bs[bn*8 + (j0 ^ (bn & 7))]       = breg[0];
            Bs[bn*8 + ((j0 + 1) ^ (bn & 7))] = breg[1];
        }
        __syncthreads();
        if (kt + 1 < niter) load_regs(kt + 1);
        #pragma unroll
        for (int ks = 0; ks < 2; ++ks) {
            const int chunk = (lk + 4*ks) ^ swz;
            bf16x8 af[4], bfr[3];
            #pragma unroll
            for (int mt = 0; mt < 4; ++mt)
                af[mt] = As[(w*64 + mt*16 + lm)*8 + chunk];
            #pragma unroll
            for (int nt = 0; nt < 3; ++nt)
                bfr[nt] = Bs[(nt*16 + lm)*8 + chunk];
            #pragma unroll
            for (int mt = 0; mt < 4; ++mt)
                #pragma unroll
                for (int nt = 0; nt < 3; ++nt)
                    acc[mt][nt] = __builtin_amdgcn_mfma_f32_16x16x32_bf16(
                        af[mt], bfr[nt], acc[mt][nt], 0, 0, 0);
        }
    }

    float* pcp = pc + (size_t)kpart*NPCH;
    #pragma unroll
    for (int nt = 0; nt < 3; ++nt) {
        const int nl = nt*16 + lm;
        const int rr = (nl >= 24) ? 1 : 0;
        const int ow = nl - 24*rr;
        if (ow < 22) {
            const int s = (2*ohp + rr)*22 + ow;
            #pragma unroll
            for (int mt = 0; mt < 4; ++mt) {
                #pragma unroll
                for (int r = 0; r < 4; ++r) {
                    const int m = w*64 + mt*16 + lk*4 + r;
                    pcp[((size_t)(b*256 + m))*484 + s] = acc[mt][nt][r];
                }
            }
        }
    }
}

// ---------------- primary squash
__global__ __launch_bounds__(256) void psquash_kernel(const float* __restrict__ pc,
                                                      const float* __restrict__ bias,
                                                      float* __restrict__ u,
                                                      float* __restrict__ Uacc)
{
    const int b = blockIdx.y;
    const int p = blockIdx.x*256 + threadIdx.x;
    float u8[8];
    #pragma unroll
    for (int e = 0; e < 8; ++e) u8[e] = 0.f;
    if (p < PCAPS) {
        const int m = p / 484;
        const int s = p - m*484;
        float sq = 0.f;
        #pragma unroll
        for (int e = 0; e < 8; ++e) {
            const int ch = e*32 + m;
            const size_t idx = ((size_t)(b*256 + ch))*484 + s;
            const float val = pc[idx] + pc[NPCH + idx] + pc[2*NPCH + idx] + pc[3*NPCH + idx]
                            + bias[ch];
            u8[e] = val; sq += val*val;
        }
        const float scale = (sq / (1.f + sq)) / sqrtf(sq + 1e-8f);
        #pragma unroll
        for (int e = 0; e < 8; ++e) u8[e] *= scale;
        float4* up = (float4*)(u + ((size_t)b*PCAPS + p)*8);
        up[0] = make_float4(u8[0], u8[1], u8[2], u8[3]);
        up[1] = make_float4(u8[4], u8[5], u8[6], u8[7]);
    }
    #pragma unroll
    for (int off = 32; off > 0; off >>= 1) {
        #pragma unroll
        for (int e = 0; e < 8; ++e) u8[e] += __shfl_down(u8[e], off, 64);
    }
    if ((threadIdx.x & 63) == 0) {
        #pragma unroll
        for (int e = 0; e < 8; ++e) atomicAdd(&Uacc[b*8 + e], u8[e]);
    }
}

// ---------------- routing big pass
__global__ __launch_bounds__(256) void route_pass(const float* __restrict__ u,
                                                  const float* __restrict__ Wv,
                                                  float* __restrict__ Z,
                                                  float* __restrict__ tu)
{
    const int b = blockIdx.y;
    const int t = threadIdx.x;
    __shared__ float sWv[80];
    if (t < 80) sWv[t] = Wv[b*80 + t];
    __syncthreads();
    float accZ[10];
    float accT[80];
    #pragma unroll
    for (int i = 0; i < 10; ++i) accZ[i] = 0.f;
    #pragma unroll
    for (int i = 0; i < 80; ++i) accT[i] = 0.f;
    for (int p = blockIdx.x*256 + t; p < PCAPS; p += 8*256) {
        const float4* up = (const float4*)(u + ((size_t)b*PCAPS + p)*8);
        const float4 ua = up[0], ub = up[1];
        const float u8[8] = {ua.x, ua.y, ua.z, ua.w, ub.x, ub.y, ub.z, ub.w};
        #pragma unroll
        for (int c = 0; c < 10; ++c) {
            float bij = 0.f;
            #pragma unroll
            for (int e = 0; e < 8; ++e) bij = fmaf(u8[e], sWv[c*8 + e], bij);
            const float ex = __expf(bij);
            accZ[c] += ex;
            #pragma unroll
            for (int e = 0; e < 8; ++e) accT[c*8 + e] = fmaf(ex, u8[e], accT[c*8 + e]);
        }
    }
    #pragma unroll
    for (int off = 32; off > 0; off >>= 1) {
        #pragma unroll
        for (int i = 0; i < 10; ++i) accZ[i] += __shfl_down(accZ[i], off, 64);
        #pragma unroll
        for (int i = 0; i < 80; ++i) accT[i] += __shfl_down(accT[i], off, 64);
    }
    if ((t & 63) == 0) {
        #pragma unroll
        for (int c = 0; c < 10; ++c) atomicAdd(&Z[b*10 + c], accZ[c]);
        #pragma unroll
        for (int i = 0; i < 80; ++i) atomicAdd(&tu[b*80 + i], accT[i]);
    }
}

// ---------------- tiny per-(b,c) routing step
__global__ void route_small_kernel(const float* __restrict__ W,
                                   const float* __restrict__ tu,
                                   const float* __restrict__ Z,
                                   const float* __restrict__ Uacc,
                                   float* __restrict__ v,
                                   float* __restrict__ WvSum,
                                   int mode)   // 0: uniform c_ij, 1: accumulate, 2: final
{
    const int t = threadIdx.x;
    if (t >= 160) return;
    const int b = t / 10, c = t - b*10;
    float te[8];
    float zinv;
    if (mode == 0) {
        #pragma unroll
        for (int e = 0; e < 8; ++e) te[e] = Uacc[b*8 + e];
        zinv = 1.f / (float)PCAPS;
    } else {
        #pragma unroll
        for (int e = 0; e < 8; ++e) te[e] = tu[(b*10 + c)*8 + e];
        zinv = 1.f / Z[b*10 + c];
    }
    float s[16];
    float sq = 0.f;
    #pragma unroll
    for (int d = 0; d < 16; ++d) {
        float a = 0.f;
        #pragma unroll
        for (int e = 0; e < 8; ++e) a = fmaf(W[(c*16 + d)*8 + e], te[e], a);
        a *= zinv;
        s[d] = a; sq += a*a;
    }
    const float scale = (sq / (1.f + sq)) / sqrtf(sq + 1e-8f);
    #pragma unroll
    for (int d = 0; d < 16; ++d) { s[d] *= scale; v[(b*10 + c)*16 + d] = s[d]; }
    if (mode != 2) {
        #pragma unroll
        for (int e = 0; e < 8; ++e) {
            float a = 0.f;
            #pragma unroll
            for (int d = 0; d < 16; ++d) a = fmaf(W[(c*16 + d)*8 + e], s[d], a);
            WvSum[(b*10 + c)*8 + e] = (mode == 0) ? a : (WvSum[(b*10 + c)*8 + e] + a);
        }
    }
}

// ---------------- head: v_length, argmax, one-hot, masked caps
__global__ __launch_bounds__(256) void head_kernel(const float* __restrict__ v,
                                                   float* __restrict__ y_out,
                                                   float* __restrict__ vlen_out,
                                                   float* __restrict__ m)
{
    __shared__ float lv[160];
    __shared__ int amax[16];
    const int t = threadIdx.x;
    if (t < 160) {
        const int b = t / 10, c = t - b*10;
        float s = 0.f;
        #pragma unroll
        for (int d = 0; d < 16; ++d) { const float xv = v[(b*10 + c)*16 + d]; s += xv*xv; }
        const float L = sqrtf(s);
        lv[t] = L;
        vlen_out[t] = L;
    }
    __syncthreads();
    if (t < 16) {
        int best = 0; float bv = lv[t*10];
        for (int c = 1; c < 10; ++c) { const float val = lv[t*10 + c]; if (val > bv) { bv = val; best = c; } }
        amax[t] = best;
    }
    __syncthreads();
    if (t < 160) y_out[t] = ((t % 10) == amax[t / 10]) ? 1.0f : 0.0f;
    for (int i = t; i < 2560; i += 256) {
        const int b = i / 160, cd = i - b*160, c = cd / 16;
        m[i] = (c == amax[b]) ? v[b*160 + cd] : 0.0f;
    }
}

// ---------------- z[b][j] = bias[j] prefill
__global__ __launch_bounds__(256) void fill_bias(float* __restrict__ z,
                                                 const float* __restrict__ bias, int N)
{
    const int i = blockIdx.x*256 + threadIdx.x;
    if (i < 16*N) z[i] = bias[i - (i / N) * N];
}

// ---------------- batched decoder layer: z[b][j] += sum_k act(in[b][k]) * W[k][j]
// grid (ceil(N/64), NBK), 256 threads: j = t&63 (+64*bx), kg = t>>6.
__global__ __launch_bounds__(256) void fcb_kernel(const float* __restrict__ in,
                                                  const float* __restrict__ Wm,
                                                  float* __restrict__ z,
                                                  int K, int N, int NBK, int actin)
{
    __shared__ float sin_[256*16];     // [kk][b]
    __shared__ float red[4*64*16];
    const int t = threadIdx.x;
    const int kRange = K / NBK;        // <= 256
    const int k0 = blockIdx.y * kRange;
    for (int i = t; i < 16*kRange; i += 256) {
        const int b = i & 15, kk = i >> 4;
        float val = in[b*K + k0 + kk];
        if (actin) val = fmaxf(val, 0.f);
        sin_[kk*16 + b] = val;
    }
    __syncthreads();
    const int j = blockIdx.x*64 + (t & 63);
    const int kg = t >> 6;
    const int kcnt = kRange >> 2;      // 40 or 64
    const int ks = kg * kcnt;
    float acc[16];
    #pragma unroll
    for (int b = 0; b < 16; ++b) acc[b] = 0.f;
    if (j < N) {
        const float* wp = Wm + (size_t)(k0 + ks)*N + j;
        #pragma unroll 4
        for (int kk = 0; kk < kcnt; ++kk) {
            const float wv = wp[(size_t)kk*N];
            const float4* sp = (const float4*)&sin_[(ks + kk)*16];
            const float4 s0 = sp[0], s1 = sp[1], s2 = sp[2], s3 = sp[3];
            acc[0]  = fmaf(wv, s0.x, acc[0]);  acc[1]  = fmaf(wv, s0.y, acc[1]);
            acc[2]  = fmaf(wv, s0.z, acc[2]);  acc[3]  = fmaf(wv, s0.w, acc[3]);
            acc[4]  = fmaf(wv, s1.x, acc[4]);  acc[5]  = fmaf(wv, s1.y, acc[5]);
            acc[6]  = fmaf(wv, s1.z, acc[6]);  acc[7]  = fmaf(wv, s1.w, acc[7]);
            acc[8]  = fmaf(wv, s2.x, acc[8]);  acc[9]  = fmaf(wv, s2.y, acc[9]);
            acc[10] = fmaf(wv, s2.z, acc[10]); acc[11] = fmaf(wv, s2.w, acc[11]);
            acc[12] = fmaf(wv, s3.x, acc[12]); acc[13] = fmaf(wv, s3.y, acc[13]);
            acc[14] = fmaf(wv, s3.z, acc[14]); acc[15] = fmaf(wv, s3.w, acc[15]);
        }
    }
    #pragma unroll
    for (int b = 0; b < 16; ++b) red[((kg*64) + (t & 63))*16 + b] = acc[b];
    __syncthreads();
    if (t < 64 && j < N) {
        #pragma unroll
        for (int b = 0; b < 16; ++b) {
            const float s = red[(t)*16 + b] + red[(64 + t)*16 + b]
                          + red[(128 + t)*16 + b] + red[(192 + t)*16 + b];
            atomicAdd(&z[(size_t)b*N + j], s);
        }
    }
}

// ---------------- sigmoid epilogue
__global__ __launch_bounds__(256) void sigmoid_kernel(const float* __restrict__ zin,
                                                      float* __restrict__ outp, int n)
{
    const int i = blockIdx.x*256 + threadIdx.x;
    if (i < n) outp[i] = 1.f / (1.f + __expf(-zin[i]));
}

extern "C" void kernel_launch(void* const* d_in, const int* in_sizes, int n_in,
                              void* d_out, int out_size, void* d_ws, size_t ws_size,
                              hipStream_t stream)
{
    const float* imgs = (const float*)d_in[0];
    const float* c1w  = (const float*)d_in[1];
    const float* c1b  = (const float*)d_in[2];
    const float* pw   = (const float*)d_in[3];
    const float* pb   = (const float*)d_in[4];
    const float* Wd   = (const float*)d_in[5];
    const float* w1   = (const float*)d_in[6];
    const float* b1   = (const float*)d_in[7];
    const float* w2   = (const float*)d_in[8];
    const float* b2   = (const float*)d_in[9];
    const float* w3   = (const float*)d_in[10];
    const float* b3   = (const float*)d_in[11];

    char* wsb = (char*)d_ws;
    float* out = (float*)d_out;

    __hip_bfloat16* xcb = (__hip_bfloat16*)(wsb + OFF_XC_B);
    __hip_bfloat16* wAb = (__hip_bfloat16*)(wsb + OFF_WA_B);
    float* pc = (float*)(wsb + OFF_PC_B);
    float* u  = (float*)(wsb + OFF_U_B);
    float* sm = (float*)(wsb + OFF_SM_B);

    float* Uacc = sm + S_UACC;
    float* Z1   = sm + S_Z1;
    float* tu1  = sm + S_TU1;
    float* Z2   = sm + S_Z2;
    float* tu2  = sm + S_TU2;
    float* Wvs  = sm + S_WVS;
    float* v    = sm + S_V;
    float* m    = sm + S_M;
    float* zd1  = sm + S_ZD1;
    float* zd2  = sm + S_ZD2;
    float* zd3  = sm + S_ZD3;
    float* w1T  = sm + S_W1T;

    hipMemsetAsync(xcb, 0, XC_BYTES, stream);
    hipMemsetAsync(sm, 0, 3008 * sizeof(float), stream);

    wprep_kernel<<<dim3(256), 256, 0, stream>>>(pw, wAb);
    wprep1_kernel<<<dim3(81), 256, 0, stream>>>(c1w, w1T);
    conv1_cl<<<dim3(52, 16), 256, 0, stream>>>(imgs, w1T, c1b, xcb);
    pconv_mfma<<<dim3(176, 4), 256, 0, stream>>>(xcb, wAb, pc);
    psquash_kernel<<<dim3(61, 16), 256, 0, stream>>>(pc, pb, u, Uacc);

    // routing iter 0 (uniform c_ij)
    route_small_kernel<<<1, 192, 0, stream>>>(Wd, tu1, Z1, Uacc, v, Wvs, 0);
    // routing iter 1
    route_pass<<<dim3(8, 16), 256, 0, stream>>>(u, Wvs, Z1, tu1);
    route_small_kernel<<<1, 192, 0, stream>>>(Wd, tu1, Z1, Uacc, v, Wvs, 1);
    // routing iter 2 (final)
    route_pass<<<dim3(8, 16), 256, 0, stream>>>(u, Wvs, Z2, tu2);
    route_small_kernel<<<1, 192, 0, stream>>>(Wd, tu2, Z2, Uacc, v, Wvs, 2);

    // head + decoder. out layout: [y_ohe 160][reconst 57600][v_length 160]
    head_kernel<<<1, 256, 0, stream>>>(v, out, out + 160 + 57600, m);

    fill_bias<<<dim3((16*512 + 255)/256), 256, 0, stream>>>(zd1, b1, 512);
    fcb_kernel<<<dim3(8, 1), 256, 0, stream>>>(m, w1, zd1, 160, 512, 1, 0);
    fill_bias<<<dim3((16*1024 + 255)/256), 256, 0, stream>>>(zd2, b2, 1024);
    fcb_kernel<<<dim3(16, 2), 256, 0, stream>>>(zd1, w2, zd2, 512, 1024, 2, 1);
    fill_bias<<<dim3((16*3600 + 255)/256), 256, 0, stream>>>(zd3, b3, 3600);
    fcb_kernel<<<dim3(57, 4), 256, 0, stream>>>(zd2, w3, zd3, 1024, 3600, 4, 1);
    sigmoid_kernel<<<dim3((57600 + 255)/256), 256, 0, stream>>>(zd3, out + 160, 57600);
}